// Round 8
// baseline (488.373 us; speedup 1.0000x reference)
//
#include <hip/hip_runtime.h>
#include <hip/hip_fp16.h>
#include <math.h>

// SelfAttentionModel B=4,S=4096,H=1,E=256. fp32 in/out (harness ABI), fp16 compute.
// Factored: scores = Xq*(Wq^T Wk/16)*Xk^T ; out = (P*Xv)*(Wo Wv)^T + bo.
// ws: Wmt(128KB) + Wov(128KB) + Kh fp16 [B][S][E] (8MB) + Vt fp16 [B][E][S] (8MB).
// attn: grid 512 (2 blocks/CU, 2 waves/SIMD), block = 4 waves ALL on the same
// 32 q-rows; kv split 4-ways across waves (1024 keys each, 16 iters).
// Barrier-free K-loop (K/V B-frags direct from global, L2-hot; Q' LDS-resident;
// P round-trip wave-private; DPP softmax; cross-iter K prefetch).
// End: 4-way flash merge via LDS strips; prologue/epilogue f-split across waves.

typedef __attribute__((ext_vector_type(8))) short short8;   // 8 fp16 = MFMA A/B frag
typedef __attribute__((ext_vector_type(4))) float floatx4;  // MFMA C/D frag
typedef __attribute__((ext_vector_type(4))) float float4v;

#define LOG2E 1.4426950408889634f

__device__ __forceinline__ short f2h(float f) {
    union { __half h; short s; } u; u.h = __float2half(f); return u.s;
}

template <int CTRL>
__device__ __forceinline__ float dpp_mov(float x) {
    return __builtin_bit_cast(float,
        __builtin_amdgcn_update_dpp(0, __builtin_bit_cast(int, x), CTRL, 0xF, 0xF, true));
}
__device__ __forceinline__ float row16_max(float v) {
    v = fmaxf(v, dpp_mov<0xB1>(v));    // quad_perm xor1
    v = fmaxf(v, dpp_mov<0x4E>(v));    // quad_perm xor2
    v = fmaxf(v, dpp_mov<0x124>(v));   // row_ror:4
    v = fmaxf(v, dpp_mov<0x128>(v));   // row_ror:8
    return v;
}
__device__ __forceinline__ float row16_sum(float v) {
    v += dpp_mov<0xB1>(v);
    v += dpp_mov<0x4E>(v);
    v += dpp_mov<0x124>(v);
    v += dpp_mov<0x128>(v);
    return v;
}

// ---------------------------------------------------------------------------
// Fused pre-pass (identical to R6/R7; verified).
// ---------------------------------------------------------------------------
__global__ __launch_bounds__(256) void pre_kernel(
    const float* __restrict__ Wq, const float* __restrict__ Wk,
    const float* __restrict__ Wv, const float* __restrict__ Wo,
    const float* __restrict__ Xk, const float* __restrict__ Xv,
    short* __restrict__ Wmt, short* __restrict__ Wov,
    short* __restrict__ Kh, short* __restrict__ Vt)
{
    __shared__ short T[64 * 72];
    const int tid = threadIdx.x;
    const int blk = blockIdx.x;
    if (blk < 512) {
        float acc = 0.f;
        if (blk < 256) {
            const int a = blk;
            #pragma unroll 8
            for (int f = 0; f < 256; ++f)
                acc += Wk[f * 256 + a] * Wq[f * 256 + tid];
            Wmt[a * 256 + tid] = f2h(acc * 0.0625f);
        } else {
            const int f = blk - 256;
            #pragma unroll 8
            for (int j = 0; j < 256; ++j)
                acc += Wo[f * 256 + j] * Wv[j * 256 + tid];
            Wov[f * 256 + tid] = f2h(acc);
        }
    } else if (blk < 4608) {
        const long i = ((long)(blk - 512) * 256 + tid) * 4;
        float4v v = *(const float4v*)(Xk + i);
        union { short4 s4; short s[4]; } h;
        h.s[0] = f2h(v[0]); h.s[1] = f2h(v[1]); h.s[2] = f2h(v[2]); h.s[3] = f2h(v[3]);
        *(short4*)(Kh + i) = h.s4;
    } else {
        const int vb = blk - 4608;
        const int te = vb & 3, ts = (vb >> 2) & 63, b = vb >> 8;
        const int s0 = ts * 64, e0 = te * 64;
        #pragma unroll
        for (int i = 0; i < 4; ++i) {
            int idx = tid + i * 256;
            int sl = idx >> 4, f4 = idx & 15;
            float4v v = *(const float4v*)(Xv + ((long)(b * 4096 + s0 + sl) * 256 + e0 + f4 * 4));
            #pragma unroll
            for (int j = 0; j < 4; ++j)
                T[(f4 * 4 + j) * 72 + sl] = f2h(v[j]);
        }
        __syncthreads();
        #pragma unroll
        for (int i = 0; i < 2; ++i) {
            int idx = tid + i * 256;
            int el = idx >> 3, s8 = idx & 7;
            *(short8*)(Vt + ((long)(b * 256 + e0 + el) * 4096 + s0 + s8 * 8)) =
                *(const short8*)(&T[el * 72 + s8 * 8]);
        }
    }
}

// ---------------------------------------------------------------------------
// attn. LDS (36352 B): QA [32][264] sh @0; Pw 4x[32][72] sh @8448;
// ML [4][32][2] fl @17664sh. Merge strips 4x[32][64] fp32 overlay @0 (32KB).
// Epilogue OA [32][264] overlay @0.
// ---------------------------------------------------------------------------
__global__ __launch_bounds__(256, 2) void attn_kernel(
    const float* __restrict__ Xq, const short* __restrict__ Kh,
    const short* __restrict__ Vt, const short* __restrict__ Wmt,
    const short* __restrict__ Wov, const float* __restrict__ bo,
    float* __restrict__ out)
{
    __shared__ short smem[18176];
    const int tid = threadIdx.x;
    const int w = tid >> 6, lane = tid & 63, c = lane & 15, q = lane >> 4;
    const int x = blockIdx.x;
    const int b = (x & 7) >> 1;                    // batch per XCD pair
    const int qt = ((x >> 3) << 1) | (x & 1);      // [0,128)
    const int wrow = b * 4096 + qt * 32;           // block's 32 q-rows

    short* QA = smem;                              // [32][264]
    short* Pw = smem + 8448 + w * 2304;            // [32][72]
    float* ML = (float*)(smem + 17664);            // [4][32][2]
    float* strips = (float*)smem;                  // 4 x [32][64] (merge phase)

    // ---- prologue: wave w computes Q' C-frags for f = w*4 .. w*4+3 ----
    {
        short8 xa[2][8];
        #pragma unroll
        for (int mi = 0; mi < 2; ++mi) {
            const float* xq = Xq + (long)(wrow + mi * 16 + c) * 256;
            #pragma unroll
            for (int kb = 0; kb < 8; ++kb) {
                const float* p = xq + kb * 32 + q * 8;
                float4v lo = *(const float4v*)p, hi = *(const float4v*)(p + 4);
                short8 t;
                t[0] = f2h(lo[0]); t[1] = f2h(lo[1]); t[2] = f2h(lo[2]); t[3] = f2h(lo[3]);
                t[4] = f2h(hi[0]); t[5] = f2h(hi[1]); t[6] = f2h(hi[2]); t[7] = f2h(hi[3]);
                xa[mi][kb] = t;
            }
        }
        #pragma unroll
        for (int f4 = 0; f4 < 4; ++f4) {
            const int f = w * 4 + f4;
            floatx4 acc[2];
            acc[0] = (floatx4){0.f, 0.f, 0.f, 0.f};
            acc[1] = (floatx4){0.f, 0.f, 0.f, 0.f};
            #pragma unroll
            for (int kb = 0; kb < 8; ++kb) {
                short8 wf = *(const short8*)(Wmt + (f * 16 + c) * 256 + kb * 32 + q * 8);
                acc[0] = __builtin_amdgcn_mfma_f32_16x16x32_f16(xa[0][kb], wf, acc[0], 0, 0, 0);
                acc[1] = __builtin_amdgcn_mfma_f32_16x16x32_f16(xa[1][kb], wf, acc[1], 0, 0, 0);
            }
            #pragma unroll
            for (int mi = 0; mi < 2; ++mi)
                #pragma unroll
                for (int r = 0; r < 4; ++r)
                    QA[(mi * 16 + q * 4 + r) * 264 + f * 16 + c] = f2h(acc[mi][r]);
        }
    }
    __syncthreads();

    floatx4 oacc[2][16];
    #pragma unroll
    for (int mi = 0; mi < 2; ++mi)
        #pragma unroll
        for (int ef = 0; ef < 16; ++ef) oacc[mi][ef] = (floatx4){0.f, 0.f, 0.f, 0.f};
    float mrow[2][4], lrow[2][4];
    #pragma unroll
    for (int mi = 0; mi < 2; ++mi)
        #pragma unroll
        for (int r = 0; r < 4; ++r) { mrow[mi][r] = -1e30f; lrow[mi][r] = 0.f; }

    // wave w owns keys [w*1024, (w+1)*1024)
    const short* kp = Kh + ((long)(b * 4096 + w * 1024 + c)) * 256 + q * 8;
    const short* vp = Vt + ((long)b * 256 + c) * 4096 + w * 1024 + q * 8;

    short8 kfn[4];
    #pragma unroll
    for (int nf = 0; nf < 4; ++nf)
        kfn[nf] = *(const short8*)(kp + (long)nf * 16 * 256);

    for (int t = 0; t < 16; ++t) {
        const short* kt = kp + (long)t * 64 * 256;
        const short* vt_ = vp + t * 64;

        // ---- scores: 32 rows x 64 keys, one-ahead + cross-iter K prefetch ----
        floatx4 s[2][4];
        #pragma unroll
        for (int mi = 0; mi < 2; ++mi)
            #pragma unroll
            for (int nf = 0; nf < 4; ++nf) s[mi][nf] = (floatx4){0.f, 0.f, 0.f, 0.f};
        #pragma unroll
        for (int kb = 0; kb < 8; ++kb) {
            short8 kf[4];
            #pragma unroll
            for (int nf = 0; nf < 4; ++nf) kf[nf] = kfn[nf];
            if (kb < 7) {
                #pragma unroll
                for (int nf = 0; nf < 4; ++nf)
                    kfn[nf] = *(const short8*)(kt + (long)nf * 16 * 256 + (kb + 1) * 32);
            } else if (t + 1 < 16) {
                #pragma unroll
                for (int nf = 0; nf < 4; ++nf)
                    kfn[nf] = *(const short8*)(kt + (long)(64 * 256) + (long)nf * 16 * 256);
            }
            short8 qf0 = *(const short8*)(&QA[c * 264 + kb * 32 + q * 8]);
            short8 qf1 = *(const short8*)(&QA[(16 + c) * 264 + kb * 32 + q * 8]);
            #pragma unroll
            for (int nf = 0; nf < 4; ++nf) {
                s[0][nf] = __builtin_amdgcn_mfma_f32_16x16x32_f16(qf0, kf[nf], s[0][nf], 0, 0, 0);
                s[1][nf] = __builtin_amdgcn_mfma_f32_16x16x32_f16(qf1, kf[nf], s[1][nf], 0, 0, 0);
            }
        }

        // early-issue V frags for ef=0,1 (hide L2 latency behind softmax)
        short8 vfn[2][2];
        vfn[0][0] = *(const short8*)(vt_);
        vfn[0][1] = *(const short8*)(vt_ + 32);
        vfn[1][0] = *(const short8*)(vt_ + (long)16 * 4096);
        vfn[1][1] = *(const short8*)(vt_ + (long)16 * 4096 + 32);

        // ---- online softmax (DPP; rows = mi*16 + q*4 + r) ----
        float alpha[2][4];
        bool need = false;
        #pragma unroll
        for (int mi = 0; mi < 2; ++mi)
            #pragma unroll
            for (int r = 0; r < 4; ++r) {
                float mx = fmaxf(fmaxf(s[mi][0][r], s[mi][1][r]), fmaxf(s[mi][2][r], s[mi][3][r]));
                float mt_ = row16_max(mx);
                float mn = fmaxf(mrow[mi][r], mt_);
                float a = exp2f((mrow[mi][r] - mn) * LOG2E);
                alpha[mi][r] = a;
                float p0 = exp2f((s[mi][0][r] - mn) * LOG2E);
                float p1 = exp2f((s[mi][1][r] - mn) * LOG2E);
                float p2 = exp2f((s[mi][2][r] - mn) * LOG2E);
                float p3 = exp2f((s[mi][3][r] - mn) * LOG2E);
                s[mi][0][r] = p0; s[mi][1][r] = p1; s[mi][2][r] = p2; s[mi][3][r] = p3;
                lrow[mi][r] = lrow[mi][r] * a + row16_sum(p0 + p1 + p2 + p3);
                mrow[mi][r] = mn;
                need |= (a < 1.0f);
            }

        // P -> wave-private LDS (C-layout -> A-layout; lgkmcnt orders, no barrier)
        #pragma unroll
        for (int mi = 0; mi < 2; ++mi)
            #pragma unroll
            for (int r = 0; r < 4; ++r)
                #pragma unroll
                for (int nf = 0; nf < 4; ++nf)
                    Pw[(mi * 16 + q * 4 + r) * 72 + nf * 16 + c] = f2h(s[mi][nf][r]);

        if (__ballot(need)) {
            #pragma unroll
            for (int mi = 0; mi < 2; ++mi)
                #pragma unroll
                for (int ef = 0; ef < 16; ++ef)
                    #pragma unroll
                    for (int r = 0; r < 4; ++r)
                        oacc[mi][ef][r] *= alpha[mi][r];
        }

        short8 pf[2][2];
        #pragma unroll
        for (int mi = 0; mi < 2; ++mi)
            #pragma unroll
            for (int kb = 0; kb < 2; ++kb)
                pf[mi][kb] = *(const short8*)(&Pw[(mi * 16 + c) * 72 + kb * 32 + q * 8]);

        // ---- PV: O += P x V^T (two-ahead staged global B-frags) ----
        #pragma unroll
        for (int ef = 0; ef < 16; ++ef) {
            short8 vf0 = vfn[ef & 1][0], vf1 = vfn[ef & 1][1];
            if (ef < 14) {
                vfn[ef & 1][0] = *(const short8*)(vt_ + (long)(ef + 2) * 16 * 4096);
                vfn[ef & 1][1] = *(const short8*)(vt_ + (long)(ef + 2) * 16 * 4096 + 32);
            }
            #pragma unroll
            for (int mi = 0; mi < 2; ++mi) {
                oacc[mi][ef] = __builtin_amdgcn_mfma_f32_16x16x32_f16(pf[mi][0], vf0, oacc[mi][ef], 0, 0, 0);
                oacc[mi][ef] = __builtin_amdgcn_mfma_f32_16x16x32_f16(pf[mi][1], vf1, oacc[mi][ef], 0, 0, 0);
            }
        }
    }

    // ---- 4-way flash merge ----
    if (c == 0) {
        #pragma unroll
        for (int mi = 0; mi < 2; ++mi)
            #pragma unroll
            for (int r = 0; r < 4; ++r) {
                ML[(w * 32 + mi * 16 + q * 4 + r) * 2 + 0] = mrow[mi][r];
                ML[(w * 32 + mi * 16 + q * 4 + r) * 2 + 1] = lrow[mi][r];
            }
    }
    __syncthreads();
    float bS[2][4], lnew[2][4];
    #pragma unroll
    for (int mi = 0; mi < 2; ++mi)
        #pragma unroll
        for (int r = 0; r < 4; ++r) {
            const int row = mi * 16 + q * 4 + r;
            float M = -1e30f;
            #pragma unroll
            for (int w2 = 0; w2 < 4; ++w2)
                M = fmaxf(M, ML[(w2 * 32 + row) * 2 + 0]);
            float L = 0.f;
            #pragma unroll
            for (int w2 = 0; w2 < 4; ++w2)
                L += ML[(w2 * 32 + row) * 2 + 1] * exp2f((ML[(w2 * 32 + row) * 2 + 0] - M) * LOG2E);
            bS[mi][r] = exp2f((mrow[mi][r] - M) * LOG2E);
            lnew[mi][r] = L;
        }
    // scale own partials to the global max
    #pragma unroll
    for (int mi = 0; mi < 2; ++mi)
        #pragma unroll
        for (int ef = 0; ef < 16; ++ef)
            #pragma unroll
            for (int r = 0; r < 4; ++r)
                oacc[mi][ef][r] *= bS[mi][r];
    __syncthreads();  // ML reads done; strips may overwrite QA/Pw

    // column-ownership rounds: owner o owns ef frags 4o..4o+3
    #pragma unroll
    for (int rr = 1; rr < 4; ++rr) {
        const int o = (w + rr) & 3;
        #pragma unroll
        for (int mi = 0; mi < 2; ++mi)
            #pragma unroll
            for (int j = 0; j < 4; ++j)
                #pragma unroll
                for (int r = 0; r < 4; ++r)
                    strips[o * 2048 + (mi * 16 + q * 4 + r) * 64 + j * 16 + c] = oacc[mi][o * 4 + j][r];
        __syncthreads();
        #pragma unroll
        for (int mi = 0; mi < 2; ++mi)
            #pragma unroll
            for (int j = 0; j < 4; ++j)
                #pragma unroll
                for (int r = 0; r < 4; ++r)
                    oacc[mi][w * 4 + j][r] += strips[w * 2048 + (mi * 16 + q * 4 + r) * 64 + j * 16 + c];
        __syncthreads();
    }

    // normalize own 4 ef frags, write fp16 to OA (own cols -> no race)
    short* OA = smem;  // [32][264]
    #pragma unroll
    for (int mi = 0; mi < 2; ++mi)
        #pragma unroll
        for (int j = 0; j < 4; ++j)
            #pragma unroll
            for (int r = 0; r < 4; ++r)
                OA[(mi * 16 + q * 4 + r) * 264 + (w * 4 + j) * 16 + c] =
                    f2h(oacc[mi][w * 4 + j][r] / lnew[mi][r]);
    __syncthreads();

    // ---- epilogue: wave w computes out cols f = w*4..w*4+3 ----
    floatx4 a2[2][4];
    #pragma unroll
    for (int mi = 0; mi < 2; ++mi)
        #pragma unroll
        for (int f4 = 0; f4 < 4; ++f4) a2[mi][f4] = (floatx4){0.f, 0.f, 0.f, 0.f};
    #pragma unroll
    for (int kb = 0; kb < 8; ++kb) {
        short8 of0 = *(const short8*)(&OA[c * 264 + kb * 32 + q * 8]);
        short8 of1 = *(const short8*)(&OA[(16 + c) * 264 + kb * 32 + q * 8]);
        #pragma unroll
        for (int f4 = 0; f4 < 4; ++f4) {
            short8 wof = *(const short8*)(Wov + ((w * 4 + f4) * 16 + c) * 256 + kb * 32 + q * 8);
            a2[0][f4] = __builtin_amdgcn_mfma_f32_16x16x32_f16(of0, wof, a2[0][f4], 0, 0, 0);
            a2[1][f4] = __builtin_amdgcn_mfma_f32_16x16x32_f16(of1, wof, a2[1][f4], 0, 0, 0);
        }
    }
    #pragma unroll
    for (int f4 = 0; f4 < 4; ++f4) {
        float bv = bo[(w * 4 + f4) * 16 + c];
        #pragma unroll
        for (int mi = 0; mi < 2; ++mi)
            #pragma unroll
            for (int r = 0; r < 4; ++r)
                out[(long)(wrow + mi * 16 + q * 4 + r) * 256 + (w * 4 + f4) * 16 + c] =
                    a2[mi][f4][r] + bv;
    }
}

extern "C" void kernel_launch(void* const* d_in, const int* in_sizes, int n_in,
                              void* d_out, int out_size, void* d_ws, size_t ws_size,
                              hipStream_t stream) {
    const float* q_in = (const float*)d_in[0];
    const float* k_in = (const float*)d_in[1];
    const float* v_in = (const float*)d_in[2];
    const float* Wq   = (const float*)d_in[3];
    const float* Wk   = (const float*)d_in[4];
    const float* Wv   = (const float*)d_in[5];
    const float* Wo   = (const float*)d_in[6];
    const float* bo   = (const float*)d_in[7];
    float* out = (float*)d_out;
    short* ws  = (short*)d_ws;

    short* Wmt = ws;                       // [256][256] fp16
    short* Wov = ws + 65536;               // [256][256] fp16
    short* Kh  = ws + 131072;              // [4][4096][256] fp16
    short* Vt  = ws + 131072 + 4194304;    // [4][256][4096] fp16

    pre_kernel<<<5632, 256, 0, stream>>>(Wq, Wk, Wv, Wo, k_in, v_in, Wmt, Wov, Kh, Vt);
    attn_kernel<<<512, 256, 0, stream>>>(q_in, Kh, Vt, Wmt, Wov, bo, out);
}

// Round 9
// 426.409 us; speedup vs baseline: 1.1453x; 1.1453x over previous
//
#include <hip/hip_runtime.h>
#include <hip/hip_fp16.h>
#include <math.h>

// SelfAttentionModel B=4,S=4096,H=1,E=256. fp32 in/out (harness ABI), fp16 compute.
// Factored: scores = Xq*(Wq^T Wk/16)*Xk^T ; out = (P*Xv)*(Wo Wv)^T + bo.
// ws: Wmt(128KB) + Wov(128KB) + Kh fp16 [B][S][E] (8MB) + Vt fp16 [B][E][S] (8MB).
// attn: grid 512 (2 blocks/CU), block = 4 waves on the same 32 q-rows; kv split
// 4-ways (1024 keys/wave). Barrier-free K-loop. Merge = 2-step butterfly with
// COMPILE-TIME register indices only (R8's runtime-indexed merge spilled oacc
// to scratch: 402MB HBM writes).

typedef __attribute__((ext_vector_type(8))) short short8;   // 8 fp16 = MFMA A/B frag
typedef __attribute__((ext_vector_type(4))) float floatx4;  // MFMA C/D frag
typedef __attribute__((ext_vector_type(4))) float float4v;

#define LOG2E 1.4426950408889634f

__device__ __forceinline__ short f2h(float f) {
    union { __half h; short s; } u; u.h = __float2half(f); return u.s;
}

template <int CTRL>
__device__ __forceinline__ float dpp_mov(float x) {
    return __builtin_bit_cast(float,
        __builtin_amdgcn_update_dpp(0, __builtin_bit_cast(int, x), CTRL, 0xF, 0xF, true));
}
__device__ __forceinline__ float row16_max(float v) {
    v = fmaxf(v, dpp_mov<0xB1>(v));    // quad_perm xor1
    v = fmaxf(v, dpp_mov<0x4E>(v));    // quad_perm xor2
    v = fmaxf(v, dpp_mov<0x124>(v));   // row_ror:4
    v = fmaxf(v, dpp_mov<0x128>(v));   // row_ror:8
    return v;
}
__device__ __forceinline__ float row16_sum(float v) {
    v += dpp_mov<0xB1>(v);
    v += dpp_mov<0x4E>(v);
    v += dpp_mov<0x124>(v);
    v += dpp_mov<0x128>(v);
    return v;
}

// ---------------------------------------------------------------------------
// Fused pre-pass (identical to R6/R7/R8; verified).
// ---------------------------------------------------------------------------
__global__ __launch_bounds__(256) void pre_kernel(
    const float* __restrict__ Wq, const float* __restrict__ Wk,
    const float* __restrict__ Wv, const float* __restrict__ Wo,
    const float* __restrict__ Xk, const float* __restrict__ Xv,
    short* __restrict__ Wmt, short* __restrict__ Wov,
    short* __restrict__ Kh, short* __restrict__ Vt)
{
    __shared__ short T[64 * 72];
    const int tid = threadIdx.x;
    const int blk = blockIdx.x;
    if (blk < 512) {
        float acc = 0.f;
        if (blk < 256) {
            const int a = blk;
            #pragma unroll 8
            for (int f = 0; f < 256; ++f)
                acc += Wk[f * 256 + a] * Wq[f * 256 + tid];
            Wmt[a * 256 + tid] = f2h(acc * 0.0625f);
        } else {
            const int f = blk - 256;
            #pragma unroll 8
            for (int j = 0; j < 256; ++j)
                acc += Wo[f * 256 + j] * Wv[j * 256 + tid];
            Wov[f * 256 + tid] = f2h(acc);
        }
    } else if (blk < 4608) {
        const long i = ((long)(blk - 512) * 256 + tid) * 4;
        float4v v = *(const float4v*)(Xk + i);
        union { short4 s4; short s[4]; } h;
        h.s[0] = f2h(v[0]); h.s[1] = f2h(v[1]); h.s[2] = f2h(v[2]); h.s[3] = f2h(v[3]);
        *(short4*)(Kh + i) = h.s4;
    } else {
        const int vb = blk - 4608;
        const int te = vb & 3, ts = (vb >> 2) & 63, b = vb >> 8;
        const int s0 = ts * 64, e0 = te * 64;
        #pragma unroll
        for (int i = 0; i < 4; ++i) {
            int idx = tid + i * 256;
            int sl = idx >> 4, f4 = idx & 15;
            float4v v = *(const float4v*)(Xv + ((long)(b * 4096 + s0 + sl) * 256 + e0 + f4 * 4));
            #pragma unroll
            for (int j = 0; j < 4; ++j)
                T[(f4 * 4 + j) * 72 + sl] = f2h(v[j]);
        }
        __syncthreads();
        #pragma unroll
        for (int i = 0; i < 2; ++i) {
            int idx = tid + i * 256;
            int el = idx >> 3, s8 = idx & 7;
            *(short8*)(Vt + ((long)(b * 256 + e0 + el) * 4096 + s0 + s8 * 8)) =
                *(const short8*)(&T[el * 72 + s8 * 8]);
        }
    }
}

// ---------------------------------------------------------------------------
// attn. LDS (36352 B): loop phase QA [32][264]sh @0, Pw 4x[32][72]sh @8448,
// ML [4][32][2]fl @17664sh. Merge: xb 4x[16][128]fp32 overlay @0 (32KB).
// Epilogue OA [32][264]sh overlay @0.
// ---------------------------------------------------------------------------
__global__ __launch_bounds__(256, 2) void attn_kernel(
    const float* __restrict__ Xq, const short* __restrict__ Kh,
    const short* __restrict__ Vt, const short* __restrict__ Wmt,
    const short* __restrict__ Wov, const float* __restrict__ bo,
    float* __restrict__ out)
{
    __shared__ short smem[18176];
    const int tid = threadIdx.x;
    const int w = tid >> 6, lane = tid & 63, c = lane & 15, q = lane >> 4;
    const int x = blockIdx.x;
    const int b = (x & 7) >> 1;                    // batch per XCD pair
    const int qt = ((x >> 3) << 1) | (x & 1);      // [0,128)
    const int wrow = b * 4096 + qt * 32;           // block's 32 q-rows

    short* QA = smem;                              // [32][264]
    short* Pw = smem + 8448 + w * 2304;            // [32][72]
    float* ML = (float*)(smem + 17664);            // [4][32][2]

    // ---- prologue: wave w computes Q' C-frags for f = w*4 .. w*4+3 ----
    {
        short8 xa[2][8];
        #pragma unroll
        for (int mi = 0; mi < 2; ++mi) {
            const float* xq = Xq + (long)(wrow + mi * 16 + c) * 256;
            #pragma unroll
            for (int kb = 0; kb < 8; ++kb) {
                const float* p = xq + kb * 32 + q * 8;
                float4v lo = *(const float4v*)p, hi = *(const float4v*)(p + 4);
                short8 t;
                t[0] = f2h(lo[0]); t[1] = f2h(lo[1]); t[2] = f2h(lo[2]); t[3] = f2h(lo[3]);
                t[4] = f2h(hi[0]); t[5] = f2h(hi[1]); t[6] = f2h(hi[2]); t[7] = f2h(hi[3]);
                xa[mi][kb] = t;
            }
        }
        #pragma unroll
        for (int f4 = 0; f4 < 4; ++f4) {
            const int f = w * 4 + f4;
            floatx4 acc[2];
            acc[0] = (floatx4){0.f, 0.f, 0.f, 0.f};
            acc[1] = (floatx4){0.f, 0.f, 0.f, 0.f};
            #pragma unroll
            for (int kb = 0; kb < 8; ++kb) {
                short8 wf = *(const short8*)(Wmt + (f * 16 + c) * 256 + kb * 32 + q * 8);
                acc[0] = __builtin_amdgcn_mfma_f32_16x16x32_f16(xa[0][kb], wf, acc[0], 0, 0, 0);
                acc[1] = __builtin_amdgcn_mfma_f32_16x16x32_f16(xa[1][kb], wf, acc[1], 0, 0, 0);
            }
            #pragma unroll
            for (int mi = 0; mi < 2; ++mi)
                #pragma unroll
                for (int r = 0; r < 4; ++r)
                    QA[(mi * 16 + q * 4 + r) * 264 + f * 16 + c] = f2h(acc[mi][r]);
        }
    }
    __syncthreads();

    floatx4 oacc[2][16];
    #pragma unroll
    for (int mi = 0; mi < 2; ++mi)
        #pragma unroll
        for (int ef = 0; ef < 16; ++ef) oacc[mi][ef] = (floatx4){0.f, 0.f, 0.f, 0.f};
    float mrow[2][4], lrow[2][4];
    #pragma unroll
    for (int mi = 0; mi < 2; ++mi)
        #pragma unroll
        for (int r = 0; r < 4; ++r) { mrow[mi][r] = -1e30f; lrow[mi][r] = 0.f; }

    // wave w owns keys [w*1024, (w+1)*1024)
    const short* kp = Kh + ((long)(b * 4096 + w * 1024 + c)) * 256 + q * 8;
    const short* vp = Vt + ((long)b * 256 + c) * 4096 + w * 1024 + q * 8;

    short8 kfn[4];
    #pragma unroll
    for (int nf = 0; nf < 4; ++nf)
        kfn[nf] = *(const short8*)(kp + (long)nf * 16 * 256);

    for (int t = 0; t < 16; ++t) {
        const short* kt = kp + (long)t * 64 * 256;
        const short* vt_ = vp + t * 64;

        // ---- scores: 32 rows x 64 keys, one-ahead + cross-iter K prefetch ----
        floatx4 s[2][4];
        #pragma unroll
        for (int mi = 0; mi < 2; ++mi)
            #pragma unroll
            for (int nf = 0; nf < 4; ++nf) s[mi][nf] = (floatx4){0.f, 0.f, 0.f, 0.f};
        #pragma unroll
        for (int kb = 0; kb < 8; ++kb) {
            short8 kf[4];
            #pragma unroll
            for (int nf = 0; nf < 4; ++nf) kf[nf] = kfn[nf];
            if (kb < 7) {
                #pragma unroll
                for (int nf = 0; nf < 4; ++nf)
                    kfn[nf] = *(const short8*)(kt + (long)nf * 16 * 256 + (kb + 1) * 32);
            } else if (t + 1 < 16) {
                #pragma unroll
                for (int nf = 0; nf < 4; ++nf)
                    kfn[nf] = *(const short8*)(kt + (long)(64 * 256) + (long)nf * 16 * 256);
            }
            short8 qf0 = *(const short8*)(&QA[c * 264 + kb * 32 + q * 8]);
            short8 qf1 = *(const short8*)(&QA[(16 + c) * 264 + kb * 32 + q * 8]);
            #pragma unroll
            for (int nf = 0; nf < 4; ++nf) {
                s[0][nf] = __builtin_amdgcn_mfma_f32_16x16x32_f16(qf0, kf[nf], s[0][nf], 0, 0, 0);
                s[1][nf] = __builtin_amdgcn_mfma_f32_16x16x32_f16(qf1, kf[nf], s[1][nf], 0, 0, 0);
            }
        }

        // early-issue V frags for ef=0,1 (hide L2 latency behind softmax)
        short8 vfn[2][2];
        vfn[0][0] = *(const short8*)(vt_);
        vfn[0][1] = *(const short8*)(vt_ + 32);
        vfn[1][0] = *(const short8*)(vt_ + (long)16 * 4096);
        vfn[1][1] = *(const short8*)(vt_ + (long)16 * 4096 + 32);

        // ---- online softmax (DPP; rows = mi*16 + q*4 + r) ----
        float alpha[2][4];
        bool need = false;
        #pragma unroll
        for (int mi = 0; mi < 2; ++mi)
            #pragma unroll
            for (int r = 0; r < 4; ++r) {
                float mx = fmaxf(fmaxf(s[mi][0][r], s[mi][1][r]), fmaxf(s[mi][2][r], s[mi][3][r]));
                float mt_ = row16_max(mx);
                float mn = fmaxf(mrow[mi][r], mt_);
                float a = exp2f((mrow[mi][r] - mn) * LOG2E);
                alpha[mi][r] = a;
                float p0 = exp2f((s[mi][0][r] - mn) * LOG2E);
                float p1 = exp2f((s[mi][1][r] - mn) * LOG2E);
                float p2 = exp2f((s[mi][2][r] - mn) * LOG2E);
                float p3 = exp2f((s[mi][3][r] - mn) * LOG2E);
                s[mi][0][r] = p0; s[mi][1][r] = p1; s[mi][2][r] = p2; s[mi][3][r] = p3;
                lrow[mi][r] = lrow[mi][r] * a + row16_sum(p0 + p1 + p2 + p3);
                mrow[mi][r] = mn;
                need |= (a < 1.0f);
            }

        // P -> wave-private LDS (C-layout -> A-layout; lgkmcnt orders, no barrier)
        #pragma unroll
        for (int mi = 0; mi < 2; ++mi)
            #pragma unroll
            for (int r = 0; r < 4; ++r)
                #pragma unroll
                for (int nf = 0; nf < 4; ++nf)
                    Pw[(mi * 16 + q * 4 + r) * 72 + nf * 16 + c] = f2h(s[mi][nf][r]);

        if (__ballot(need)) {
            #pragma unroll
            for (int mi = 0; mi < 2; ++mi)
                #pragma unroll
                for (int ef = 0; ef < 16; ++ef)
                    #pragma unroll
                    for (int r = 0; r < 4; ++r)
                        oacc[mi][ef][r] *= alpha[mi][r];
        }

        short8 pf[2][2];
        #pragma unroll
        for (int mi = 0; mi < 2; ++mi)
            #pragma unroll
            for (int kb = 0; kb < 2; ++kb)
                pf[mi][kb] = *(const short8*)(&Pw[(mi * 16 + c) * 72 + kb * 32 + q * 8]);

        // ---- PV: O += P x V^T (two-ahead staged global B-frags) ----
        #pragma unroll
        for (int ef = 0; ef < 16; ++ef) {
            short8 vf0 = vfn[ef & 1][0], vf1 = vfn[ef & 1][1];
            if (ef < 14) {
                vfn[ef & 1][0] = *(const short8*)(vt_ + (long)(ef + 2) * 16 * 4096);
                vfn[ef & 1][1] = *(const short8*)(vt_ + (long)(ef + 2) * 16 * 4096 + 32);
            }
            #pragma unroll
            for (int mi = 0; mi < 2; ++mi) {
                oacc[mi][ef] = __builtin_amdgcn_mfma_f32_16x16x32_f16(pf[mi][0], vf0, oacc[mi][ef], 0, 0, 0);
                oacc[mi][ef] = __builtin_amdgcn_mfma_f32_16x16x32_f16(pf[mi][1], vf1, oacc[mi][ef], 0, 0, 0);
            }
        }
    }

    // ---- global (M,L) per row via ML, pre-scale partials ----
    if (c == 0) {
        #pragma unroll
        for (int mi = 0; mi < 2; ++mi)
            #pragma unroll
            for (int r = 0; r < 4; ++r) {
                ML[(w * 32 + mi * 16 + q * 4 + r) * 2 + 0] = mrow[mi][r];
                ML[(w * 32 + mi * 16 + q * 4 + r) * 2 + 1] = lrow[mi][r];
            }
    }
    __syncthreads();
    float lnew[2][4];
    #pragma unroll
    for (int mi = 0; mi < 2; ++mi)
        #pragma unroll
        for (int r = 0; r < 4; ++r) {
            const int row = mi * 16 + q * 4 + r;
            float M = -1e30f;
            #pragma unroll
            for (int w2 = 0; w2 < 4; ++w2)
                M = fmaxf(M, ML[(w2 * 32 + row) * 2 + 0]);
            float L = 0.f;
            #pragma unroll
            for (int w2 = 0; w2 < 4; ++w2)
                L += ML[(w2 * 32 + row) * 2 + 1] * exp2f((ML[(w2 * 32 + row) * 2 + 0] - M) * LOG2E);
            float bS = exp2f((mrow[mi][r] - M) * LOG2E);
            lnew[mi][r] = L;
            #pragma unroll
            for (int ef = 0; ef < 16; ++ef)
                oacc[mi][ef][r] *= bS;
        }
    __syncthreads();  // all loop-phase LDS reads done; xb may overlay QA/Pw

    // ---- Step 1 (partner w^1): exchange by mi. All reg indices compile-time.
    // After: wave w holds rows mi=(w&1) merged over its kv pair {w&~1, w|1}.
    float* xb = (float*)smem;  // 4 x [16][128] fp32 (8KB per wave region)
    #pragma unroll
    for (int h = 0; h < 2; ++h) {
        if (w & 1) {
            #pragma unroll
            for (int e8 = 0; e8 < 8; ++e8)
                #pragma unroll
                for (int r = 0; r < 4; ++r)
                    xb[w * 2048 + (q * 4 + r) * 128 + e8 * 16 + c] = oacc[0][h * 8 + e8][r];
        } else {
            #pragma unroll
            for (int e8 = 0; e8 < 8; ++e8)
                #pragma unroll
                for (int r = 0; r < 4; ++r)
                    xb[w * 2048 + (q * 4 + r) * 128 + e8 * 16 + c] = oacc[1][h * 8 + e8][r];
        }
        __syncthreads();
        if (w & 1) {
            #pragma unroll
            for (int e8 = 0; e8 < 8; ++e8)
                #pragma unroll
                for (int r = 0; r < 4; ++r)
                    oacc[1][h * 8 + e8][r] += xb[(w ^ 1) * 2048 + (q * 4 + r) * 128 + e8 * 16 + c];
        } else {
            #pragma unroll
            for (int e8 = 0; e8 < 8; ++e8)
                #pragma unroll
                for (int r = 0; r < 4; ++r)
                    oacc[0][h * 8 + e8][r] += xb[(w ^ 1) * 2048 + (q * 4 + r) * 128 + e8 * 16 + c];
        }
        __syncthreads();
    }

    // copy kept-mi accumulator into macc (ct indices per branch)
    floatx4 macc[16];
    if (w & 1) {
        #pragma unroll
        for (int ef = 0; ef < 16; ++ef) macc[ef] = oacc[1][ef];
    } else {
        #pragma unroll
        for (int ef = 0; ef < 16; ++ef) macc[ef] = oacc[0][ef];
    }

    // ---- Step 2 (partner w^2): exchange by ef-half within kept mi.
    // After: wave w holds rows mi=(w&1), ef-half (w>>1), merged over all 4 kv.
    if (w >> 1) {
        #pragma unroll
        for (int e8 = 0; e8 < 8; ++e8)
            #pragma unroll
            for (int r = 0; r < 4; ++r)
                xb[w * 2048 + (q * 4 + r) * 128 + e8 * 16 + c] = macc[e8][r];
    } else {
        #pragma unroll
        for (int e8 = 0; e8 < 8; ++e8)
            #pragma unroll
            for (int r = 0; r < 4; ++r)
                xb[w * 2048 + (q * 4 + r) * 128 + e8 * 16 + c] = macc[8 + e8][r];
    }
    __syncthreads();
    if (w >> 1) {
        #pragma unroll
        for (int e8 = 0; e8 < 8; ++e8)
            #pragma unroll
            for (int r = 0; r < 4; ++r)
                macc[8 + e8][r] += xb[(w ^ 2) * 2048 + (q * 4 + r) * 128 + e8 * 16 + c];
    } else {
        #pragma unroll
        for (int e8 = 0; e8 < 8; ++e8)
            #pragma unroll
            for (int r = 0; r < 4; ++r)
                macc[e8][r] += xb[(w ^ 2) * 2048 + (q * 4 + r) * 128 + e8 * 16 + c];
    }
    __syncthreads();  // xb reads done before OA overlay

    // ---- normalize own quarter, write OA fp16 (A-layout [32][264]) ----
    float ln[4];
    #pragma unroll
    for (int r = 0; r < 4; ++r) ln[r] = (w & 1) ? lnew[1][r] : lnew[0][r];
    short* OA = smem;
    const int rowbase = (w & 1) * 16;
    if (w >> 1) {
        #pragma unroll
        for (int e8 = 0; e8 < 8; ++e8)
            #pragma unroll
            for (int r = 0; r < 4; ++r)
                OA[(rowbase + q * 4 + r) * 264 + (8 + e8) * 16 + c] = f2h(macc[8 + e8][r] / ln[r]);
    } else {
        #pragma unroll
        for (int e8 = 0; e8 < 8; ++e8)
            #pragma unroll
            for (int r = 0; r < 4; ++r)
                OA[(rowbase + q * 4 + r) * 264 + e8 * 16 + c] = f2h(macc[e8][r] / ln[r]);
    }
    __syncthreads();

    // ---- epilogue: wave w computes out cols f = w*4..w*4+3 ----
    floatx4 a2[2][4];
    #pragma unroll
    for (int mi = 0; mi < 2; ++mi)
        #pragma unroll
        for (int f4 = 0; f4 < 4; ++f4) a2[mi][f4] = (floatx4){0.f, 0.f, 0.f, 0.f};
    #pragma unroll
    for (int kb = 0; kb < 8; ++kb) {
        short8 of0 = *(const short8*)(&OA[c * 264 + kb * 32 + q * 8]);
        short8 of1 = *(const short8*)(&OA[(16 + c) * 264 + kb * 32 + q * 8]);
        #pragma unroll
        for (int f4 = 0; f4 < 4; ++f4) {
            short8 wof = *(const short8*)(Wov + ((w * 4 + f4) * 16 + c) * 256 + kb * 32 + q * 8);
            a2[0][f4] = __builtin_amdgcn_mfma_f32_16x16x32_f16(of0, wof, a2[0][f4], 0, 0, 0);
            a2[1][f4] = __builtin_amdgcn_mfma_f32_16x16x32_f16(of1, wof, a2[1][f4], 0, 0, 0);
        }
    }
    #pragma unroll
    for (int f4 = 0; f4 < 4; ++f4) {
        float bv = bo[(w * 4 + f4) * 16 + c];
        #pragma unroll
        for (int mi = 0; mi < 2; ++mi)
            #pragma unroll
            for (int r = 0; r < 4; ++r)
                out[(long)(wrow + mi * 16 + q * 4 + r) * 256 + (w * 4 + f4) * 16 + c] =
                    a2[mi][f4][r] + bv;
    }
}

extern "C" void kernel_launch(void* const* d_in, const int* in_sizes, int n_in,
                              void* d_out, int out_size, void* d_ws, size_t ws_size,
                              hipStream_t stream) {
    const float* q_in = (const float*)d_in[0];
    const float* k_in = (const float*)d_in[1];
    const float* v_in = (const float*)d_in[2];
    const float* Wq   = (const float*)d_in[3];
    const float* Wk   = (const float*)d_in[4];
    const float* Wv   = (const float*)d_in[5];
    const float* Wo   = (const float*)d_in[6];
    const float* bo   = (const float*)d_in[7];
    float* out = (float*)d_out;
    short* ws  = (short*)d_ws;

    short* Wmt = ws;                       // [256][256] fp16
    short* Wov = ws + 65536;               // [256][256] fp16
    short* Kh  = ws + 131072;              // [4][4096][256] fp16
    short* Vt  = ws + 131072 + 4194304;    // [4][256][4096] fp16

    pre_kernel<<<5632, 256, 0, stream>>>(Wq, Wk, Wv, Wo, k_in, v_in, Wmt, Wov, Kh, Vt);
    attn_kernel<<<512, 256, 0, stream>>>(q_in, Kh, Vt, Wmt, Wov, bo, out);
}